// Round 6
// baseline (959.890 us; speedup 1.0000x reference)
//
#include <hip/hip_runtime.h>
#include <hip/hip_cooperative_groups.h>
#include <math.h>

// PointcloudToVoxels: B=4, C=32, N=200k, 64^3 grid, V=262144.
// Output: [B,C,V] voxeldata (f32) then [B,1,V] occupancy (f32).
//
// R4: device-scope atomics are memory-side (~26 G/s) -> counting sort.
// R5: materialized channel-vector sort, 364us (write amplification found).
// R6: full-line scattered writes + cooperative segmax, 336us.
// R7/R8: dense transpose + line-gather segmax, 324us. Random 128B-line
//     traffic sustains ~2.4 TB/s vs 6.6 streaming, either side of the perm.
// R9: segmax4 (LDS-staged idx, octet float4 gathers), 300us.
// R10: roofline audit says the 13-kernel pipeline is ~105-125us of memory
//     work; measured 300us; no single kernel >83us. Deficit is distributed
//     -> dispatch boundaries (drain+relaunch x12, incl. a 1-block kernel).
//     Fuse the whole fast path into ONE cooperative kernel with grid.sync()
//     between phases; phase bodies identical to R9. Fallback to R9 sequence
//     if cooperative launch is unavailable.

#define GW 64
#define GL 64
#define GH 64
#define GV (GW * GL * GH)   // 262144 = 2^18
#define NB 4
#define MIN_PTS 10

namespace cg = cooperative_groups;

// Binning that bit-matches XLA's floor(x/0.05 + 0.5) (x/0.05 folds to
// x*20.0f exactly; __fmul_rn/__fadd_rn forbid FMA contraction). [R3: absmax 0]
__device__ __forceinline__ int bin_coord(float x) {
    float m = __fmul_rn(x, 20.0f);
    float r = __fadd_rn(m, 0.5f);
    return (int)floorf(r);
}

// ---------------------------------------------------------------------------
// R10 mega-kernel: all phases in one cooperative launch.
union MegaSmem {
    float tr[4][64 * 33];               // 33792 B (hist+transpose)
    int scan[256];                      // scans
    struct {
        float acc[64 * 33];
        int cnt[64];
        int off[64];
        int sidx[512];
    } sm;                               // segmax
};

__global__ void __launch_bounds__(256, 4)
mega_kernel(const float* __restrict__ coords,
            const float* __restrict__ attrs,
            int* __restrict__ counts,
            int* __restrict__ offsets,
            int* __restrict__ blocksums,
            int* __restrict__ vox,
            int* __restrict__ rank,
            int* __restrict__ sorted_idx,
            float* __restrict__ attrsT,
            float* __restrict__ vdata,
            float* __restrict__ occ,
            int N) {
    cg::grid_group grid = cg::this_grid();
    __shared__ MegaSmem S;
    const int t = threadIdx.x;
    const int G = gridDim.x;
    const int bid = blockIdx.x;
    const size_t strideT = (size_t)N * 32;

    // ---- Phase A: zero counts (NB*GV ints) ----
    {
        uint4* c4 = (uint4*)counts;
        for (int i = bid * 256 + t; i < NB * GV / 4; i += G * 256)
            c4[i] = make_uint4(0u, 0u, 0u, 0u);
    }
    grid.sync();

    // ---- Phase B: fused histogram + dense transpose ----
    const int perB = (N + 255) / 256;
    const int w = t >> 6, l = t & 63;
    for (int vb = bid; vb < NB * perB; vb += G) {
        int b = vb / perB;
        int blk = vb - b * perB;
        int n = blk * 256 + t;
        if (n < N) {
            const float* pc = coords + (size_t)b * 3 * N;
            int ix = bin_coord(pc[n]);
            int iy = bin_coord(pc[n + N]);
            int iz = bin_coord(pc[n + 2 * N]);
            bool ok = (unsigned)ix < (unsigned)GW &&
                      (unsigned)iy < (unsigned)GL &&
                      (unsigned)iz < (unsigned)GH;
            int v = ok ? ((ix << 12) | (iy << 6) | iz) : -1;
            vox[(size_t)b * N + n] = v;
            if (ok) rank[(size_t)b * N + n] = atomicAdd(&counts[b * GV + v], 1);
            const float* pa = attrs + (size_t)b * 32 * N + n;
            float* row = &S.tr[w][l * 33];
#pragma unroll
            for (int c = 0; c < 32; ++c)
                row[c] = pa[(size_t)c * N];      // 256B coalesced per instr
        }
        __syncthreads();
        float* dbase = attrsT + (size_t)b * strideT;
        int wbase = blk * 256 + w * 64;
        int j = l & 7;
#pragma unroll
        for (int s = 0; s < 8; ++s) {
            int q = s * 8 + (l >> 3);
            int p = wbase + q;                   // dense destination
            if (p < N) {
                const float* src = &S.tr[w][q * 33 + j * 4];
                float4 val = make_float4(src[0], src[1], src[2], src[3]);
                *(float4*)&dbase[(size_t)p * 32 + j * 4] = val;
            }
        }
        __syncthreads();
    }
    grid.sync();

    // ---- Phase C1: per-tile (1024) exclusive scan + block sums ----
    for (int sb = bid; sb < NB * GV / 1024; sb += G) {
        int base = sb * 1024 + t * 4;
        int4 c = *(const int4*)&counts[base];
        int s0 = c.x, s1 = s0 + c.y, s2 = s1 + c.z, s3 = s2 + c.w;
        S.scan[t] = s3;
        __syncthreads();
        for (int d = 1; d < 256; d <<= 1) {
            int v = (t >= d) ? S.scan[t - d] : 0;
            __syncthreads();
            if (t >= d) S.scan[t] += v;
            __syncthreads();
        }
        int excl = (t > 0) ? S.scan[t - 1] : 0;
        int4 o;
        o.x = excl; o.y = excl + s0; o.z = excl + s1; o.w = excl + s2;
        *(int4*)&offsets[base] = o;
        if (t == 255) blocksums[sb] = S.scan[255];
        __syncthreads();
    }
    grid.sync();

    // ---- Phase C2: scan the 1024 tile sums (block 0 only) ----
    if (bid == 0) {
        int4 c = *(const int4*)&blocksums[t * 4];
        int s0 = c.x, s1 = s0 + c.y, s2 = s1 + c.z, s3 = s2 + c.w;
        S.scan[t] = s3;
        __syncthreads();
        for (int d = 1; d < 256; d <<= 1) {
            int v = (t >= d) ? S.scan[t - d] : 0;
            __syncthreads();
            if (t >= d) S.scan[t] += v;
            __syncthreads();
        }
        int excl = (t > 0) ? S.scan[t - 1] : 0;
        int4 o;
        o.x = excl; o.y = excl + s0; o.z = excl + s1; o.w = excl + s2;
        *(int4*)&blocksums[t * 4] = o;
    }
    grid.sync();

    // ---- Phase C3: add tile offsets ----
    for (int i = bid * 256 + t; i < NB * GV / 4; i += G * 256) {
        int s = blocksums[(i * 4) >> 10];
        int4 o = *(int4*)&offsets[i * 4];
        o.x += s; o.y += s; o.z += s; o.w += s;
        *(int4*)&offsets[i * 4] = o;
    }
    grid.sync();

    // ---- Phase D: scatter point index (4B into 3MB region, L2-merged) ----
    for (int i = bid * 256 + t; i < NB * N; i += G * 256) {
        int b = i / N;
        int n = i - b * N;
        int v = vox[i];
        if (v >= 0)
            sorted_idx[offsets[b * GV + v] + rank[i]] = n;
    }
    grid.sync();

    // ---- Phase E: segmax4 (LDS-staged idx + octet float4 gathers) ----
    const int vo = l >> 3;      // voxel within octet
    const int j = l & 7;        // float4 piece -> channels 4j..4j+3
    for (int vb = bid; vb < NB * (GV / 64); vb += G) {
        int b = vb >> 12;                   // GV/64 = 4096
        int v0 = (vb & 4095) * 64;
        __syncthreads();                    // protect S.sm reuse across vb
        if (t < 64) {
            int bv = b * GV + v0 + t;
            S.sm.cnt[t] = counts[bv];
            S.sm.off[t] = offsets[bv];
        }
        __syncthreads();
        int off0 = S.sm.off[0];
        int npts = S.sm.off[63] + S.sm.cnt[63] - off0;
        int vl0 = w * 16 + vo;
        int vl1 = w * 16 + 8 + vo;
        int ks0 = S.sm.off[vl0] - off0, ke0 = ks0 + S.sm.cnt[vl0];
        int ks1 = S.sm.off[vl1] - off0, ke1 = ks1 + S.sm.cnt[vl1];
        float4 m0 = make_float4(-INFINITY, -INFINITY, -INFINITY, -INFINITY);
        float4 m1 = m0;
        const float* sbase = attrsT + (size_t)b * strideT;
        const int* sgl = sorted_idx + off0;
        for (int base = 0; base < npts; base += 512) {
            __syncthreads();
            int mm = npts - base; if (mm > 512) mm = 512;
            for (int i = t; i < mm; i += 256) S.sm.sidx[i] = sgl[base + i];
            __syncthreads();
            int hi = base + mm;
            int lo0 = ks0 > base ? ks0 : base, h0 = ke0 < hi ? ke0 : hi;
            for (int k = lo0; k < h0; ++k) {
                int idx = S.sm.sidx[k - base];
                float4 x = *(const float4*)&sbase[(size_t)idx * 32 + j * 4];
                m0.x = fmaxf(m0.x, x.x); m0.y = fmaxf(m0.y, x.y);
                m0.z = fmaxf(m0.z, x.z); m0.w = fmaxf(m0.w, x.w);
            }
            int lo1 = ks1 > base ? ks1 : base, h1 = ke1 < hi ? ke1 : hi;
            for (int k = lo1; k < h1; ++k) {
                int idx = S.sm.sidx[k - base];
                float4 x = *(const float4*)&sbase[(size_t)idx * 32 + j * 4];
                m1.x = fmaxf(m1.x, x.x); m1.y = fmaxf(m1.y, x.y);
                m1.z = fmaxf(m1.z, x.z); m1.w = fmaxf(m1.w, x.w);
            }
        }
        int c4 = j * 4;
        bool nz0 = S.sm.cnt[vl0] > 0, nz1 = S.sm.cnt[vl1] > 0;
        S.sm.acc[vl0 * 33 + c4 + 0] = nz0 ? m0.x : 0.0f;
        S.sm.acc[vl0 * 33 + c4 + 1] = nz0 ? m0.y : 0.0f;
        S.sm.acc[vl0 * 33 + c4 + 2] = nz0 ? m0.z : 0.0f;
        S.sm.acc[vl0 * 33 + c4 + 3] = nz0 ? m0.w : 0.0f;
        S.sm.acc[vl1 * 33 + c4 + 0] = nz1 ? m1.x : 0.0f;
        S.sm.acc[vl1 * 33 + c4 + 1] = nz1 ? m1.y : 0.0f;
        S.sm.acc[vl1 * 33 + c4 + 2] = nz1 ? m1.z : 0.0f;
        S.sm.acc[vl1 * 33 + c4 + 3] = nz1 ? m1.w : 0.0f;
        __syncthreads();
        int vv = v0 + l;
#pragma unroll
        for (int cc = 0; cc < 8; ++cc) {
            int ch = cc * 4 + w;
            vdata[(((size_t)(b * 32 + ch)) << 18) + vv] = S.sm.acc[l * 33 + ch];
        }
        if (t < 64)
            occ[b * GV + v0 + t] = (S.sm.cnt[t] >= MIN_PTS) ? 1.0f : 0.0f;
    }
}

// ---------------------------------------------------------------------------
// R9 kernels (fallback path if cooperative launch unavailable).

__global__ void zero_kernel(uint4* __restrict__ p, int n4) {
    int i = blockIdx.x * blockDim.x + threadIdx.x;
    if (i < n4) p[i] = make_uint4(0u, 0u, 0u, 0u);
}

__global__ void hist_transpose_kernel(const float* __restrict__ coords,
                                      const float* __restrict__ attrs,
                                      int* __restrict__ counts,
                                      int* __restrict__ vox,
                                      int* __restrict__ rank,
                                      float* __restrict__ attrsT,
                                      size_t strideT, int b0, int N) {
    __shared__ float lds[4][64 * 33];
    int t = threadIdx.x;
    int w = t >> 6;
    int l = t & 63;
    int n = blockIdx.x * 256 + t;
    int b = b0 + blockIdx.y;
    if (n < N) {
        const float* pc = coords + (size_t)b * 3 * N;
        int ix = bin_coord(pc[n]);
        int iy = bin_coord(pc[n + N]);
        int iz = bin_coord(pc[n + 2 * N]);
        bool ok = (unsigned)ix < (unsigned)GW && (unsigned)iy < (unsigned)GL &&
                  (unsigned)iz < (unsigned)GH;
        int v = ok ? ((ix << 12) | (iy << 6) | iz) : -1;
        vox[(size_t)b * N + n] = v;
        if (ok) rank[(size_t)b * N + n] = atomicAdd(&counts[b * GV + v], 1);
        const float* pa = attrs + (size_t)b * 32 * N + n;
        float* row = &lds[w][l * 33];
#pragma unroll
        for (int c = 0; c < 32; ++c)
            row[c] = pa[(size_t)c * N];
    }
    __syncthreads();
    float* dbase = attrsT + (size_t)blockIdx.y * strideT;
    int wbase = blockIdx.x * 256 + w * 64;
    int j = l & 7;
#pragma unroll
    for (int s = 0; s < 8; ++s) {
        int q = s * 8 + (l >> 3);
        int p = wbase + q;
        if (p < N) {
            const float* src = &lds[w][q * 33 + j * 4];
            float4 val = make_float4(src[0], src[1], src[2], src[3]);
            *(float4*)&dbase[(size_t)p * 32 + j * 4] = val;
        }
    }
}

__global__ void hist_kernel(const float* __restrict__ coords,
                            int* __restrict__ counts,
                            int* __restrict__ vox,
                            int* __restrict__ rank,
                            int N) {
    int n = blockIdx.x * blockDim.x + threadIdx.x;
    int b = blockIdx.y;
    if (n >= N) return;
    const float* pc = coords + (size_t)b * 3 * N;
    int ix = bin_coord(pc[n]);
    int iy = bin_coord(pc[n + N]);
    int iz = bin_coord(pc[n + 2 * N]);
    bool ok = (unsigned)ix < (unsigned)GW && (unsigned)iy < (unsigned)GL &&
              (unsigned)iz < (unsigned)GH;
    int v = ok ? ((ix << 12) | (iy << 6) | iz) : -1;
    vox[(size_t)b * N + n] = v;
    if (ok) rank[(size_t)b * N + n] = atomicAdd(&counts[b * GV + v], 1);
}

__global__ void transpose_kernel(const float* __restrict__ attrs,
                                 float* __restrict__ attrsT,
                                 size_t strideT, int b0, int N) {
    __shared__ float lds[4][64 * 33];
    int t = threadIdx.x;
    int w = t >> 6;
    int l = t & 63;
    int n = blockIdx.x * 256 + t;
    int b = b0 + blockIdx.y;
    if (n < N) {
        const float* pa = attrs + (size_t)b * 32 * N + n;
        float* row = &lds[w][l * 33];
#pragma unroll
        for (int c = 0; c < 32; ++c)
            row[c] = pa[(size_t)c * N];
    }
    __syncthreads();
    float* dbase = attrsT + (size_t)blockIdx.y * strideT;
    int wbase = blockIdx.x * 256 + w * 64;
    int j = l & 7;
#pragma unroll
    for (int s = 0; s < 8; ++s) {
        int q = s * 8 + (l >> 3);
        int p = wbase + q;
        if (p < N) {
            const float* src = &lds[w][q * 33 + j * 4];
            float4 val = make_float4(src[0], src[1], src[2], src[3]);
            *(float4*)&dbase[(size_t)p * 32 + j * 4] = val;
        }
    }
}

__global__ void scan_blocks_kernel(const int* __restrict__ counts,
                                   int* __restrict__ offsets,
                                   int* __restrict__ blocksums) {
    __shared__ int lds[256];
    int t = threadIdx.x;
    int base = blockIdx.x * 1024 + t * 4;
    int4 c = *(const int4*)&counts[base];
    int s0 = c.x, s1 = s0 + c.y, s2 = s1 + c.z, s3 = s2 + c.w;
    lds[t] = s3;
    __syncthreads();
    for (int d = 1; d < 256; d <<= 1) {
        int v = (t >= d) ? lds[t - d] : 0;
        __syncthreads();
        if (t >= d) lds[t] += v;
        __syncthreads();
    }
    int excl = (t > 0) ? lds[t - 1] : 0;
    int4 o;
    o.x = excl; o.y = excl + s0; o.z = excl + s1; o.w = excl + s2;
    *(int4*)&offsets[base] = o;
    if (t == 255) blocksums[blockIdx.x] = lds[255];
}

__global__ void scan_sums_kernel(int* __restrict__ blocksums) {
    __shared__ int lds[256];
    int t = threadIdx.x;
    int4 c = *(const int4*)&blocksums[t * 4];
    int s0 = c.x, s1 = s0 + c.y, s2 = s1 + c.z, s3 = s2 + c.w;
    lds[t] = s3;
    __syncthreads();
    for (int d = 1; d < 256; d <<= 1) {
        int v = (t >= d) ? lds[t - d] : 0;
        __syncthreads();
        if (t >= d) lds[t] += v;
        __syncthreads();
    }
    int excl = (t > 0) ? lds[t - 1] : 0;
    int4 o;
    o.x = excl; o.y = excl + s0; o.z = excl + s1; o.w = excl + s2;
    *(int4*)&blocksums[t * 4] = o;
}

__global__ void scan_add_kernel(int* __restrict__ offsets,
                                const int* __restrict__ blocksums) {
    int i = blockIdx.x * blockDim.x + threadIdx.x;
    int s = blocksums[(i * 4) >> 10];
    int4 o = *(int4*)&offsets[i * 4];
    o.x += s; o.y += s; o.z += s; o.w += s;
    *(int4*)&offsets[i * 4] = o;
}

__global__ void scatter_idx_kernel(const int* __restrict__ vox,
                                   const int* __restrict__ rank,
                                   const int* __restrict__ offsets,
                                   int* __restrict__ sorted_idx,
                                   int N) {
    int n = blockIdx.x * blockDim.x + threadIdx.x;
    int b = blockIdx.y;
    if (n >= N) return;
    int v = vox[(size_t)b * N + n];
    if (v < 0) return;
    sorted_idx[offsets[b * GV + v] + rank[(size_t)b * N + n]] = n;
}

__global__ void segmax4_kernel(const float* __restrict__ attrsT,
                               const int* __restrict__ counts,
                               const int* __restrict__ offsets,
                               const int* __restrict__ sorted_idx,
                               float* __restrict__ vdata,
                               float* __restrict__ occ,
                               size_t strideT, int b0) {
    __shared__ float acc[64 * 33];
    __shared__ int cnt_l[64];
    __shared__ int off_l[64];
    __shared__ int sidx[512];
    int t = threadIdx.x;
    int w = t >> 6;
    int l = t & 63;
    int vo = l >> 3;
    int j = l & 7;
    int b = b0 + blockIdx.y;
    int v0 = blockIdx.x * 64;
    if (t < 64) {
        int bv = b * GV + v0 + t;
        cnt_l[t] = counts[bv];
        off_l[t] = offsets[bv];
    }
    __syncthreads();
    int off0 = off_l[0];
    int npts = off_l[63] + cnt_l[63] - off0;
    int vl0 = w * 16 + vo;
    int vl1 = w * 16 + 8 + vo;
    int ks0 = off_l[vl0] - off0, ke0 = ks0 + cnt_l[vl0];
    int ks1 = off_l[vl1] - off0, ke1 = ks1 + cnt_l[vl1];
    float4 m0 = make_float4(-INFINITY, -INFINITY, -INFINITY, -INFINITY);
    float4 m1 = m0;
    const float* sbase = attrsT + (size_t)blockIdx.y * strideT;
    const int* sgl = sorted_idx + off0;
    for (int base = 0; base < npts; base += 512) {
        __syncthreads();
        int mm = npts - base; if (mm > 512) mm = 512;
        for (int i = t; i < mm; i += 256) sidx[i] = sgl[base + i];
        __syncthreads();
        int hi = base + mm;
        int lo0 = ks0 > base ? ks0 : base, h0 = ke0 < hi ? ke0 : hi;
        for (int k = lo0; k < h0; ++k) {
            int idx = sidx[k - base];
            float4 x = *(const float4*)&sbase[(size_t)idx * 32 + j * 4];
            m0.x = fmaxf(m0.x, x.x); m0.y = fmaxf(m0.y, x.y);
            m0.z = fmaxf(m0.z, x.z); m0.w = fmaxf(m0.w, x.w);
        }
        int lo1 = ks1 > base ? ks1 : base, h1 = ke1 < hi ? ke1 : hi;
        for (int k = lo1; k < h1; ++k) {
            int idx = sidx[k - base];
            float4 x = *(const float4*)&sbase[(size_t)idx * 32 + j * 4];
            m1.x = fmaxf(m1.x, x.x); m1.y = fmaxf(m1.y, x.y);
            m1.z = fmaxf(m1.z, x.z); m1.w = fmaxf(m1.w, x.w);
        }
    }
    int c4 = j * 4;
    bool nz0 = cnt_l[vl0] > 0, nz1 = cnt_l[vl1] > 0;
    acc[vl0 * 33 + c4 + 0] = nz0 ? m0.x : 0.0f;
    acc[vl0 * 33 + c4 + 1] = nz0 ? m0.y : 0.0f;
    acc[vl0 * 33 + c4 + 2] = nz0 ? m0.z : 0.0f;
    acc[vl0 * 33 + c4 + 3] = nz0 ? m0.w : 0.0f;
    acc[vl1 * 33 + c4 + 0] = nz1 ? m1.x : 0.0f;
    acc[vl1 * 33 + c4 + 1] = nz1 ? m1.y : 0.0f;
    acc[vl1 * 33 + c4 + 2] = nz1 ? m1.z : 0.0f;
    acc[vl1 * 33 + c4 + 3] = nz1 ? m1.w : 0.0f;
    __syncthreads();
    int vv = v0 + l;
#pragma unroll
    for (int cc = 0; cc < 8; ++cc) {
        int ch = cc * 4 + w;
        vdata[(((size_t)(b * 32 + ch)) << 18) + vv] = acc[l * 33 + ch];
    }
    if (t < 64)
        occ[b * GV + v0 + t] = (cnt_l[t] >= MIN_PTS) ? 1.0f : 0.0f;
}

// v1 middle-tier segmax (small ws).
__global__ void segmax_kernel(const float* __restrict__ attrs,
                              const int* __restrict__ counts,
                              const int* __restrict__ offsets,
                              const int* __restrict__ sorted_idx,
                              float* __restrict__ vdata,
                              float* __restrict__ occ,
                              int N) {
    int t = blockIdx.x * blockDim.x + threadIdx.x;
    int v = t & (GV - 1);
    int c = (t >> 18) & 31;
    int b = t >> 23;
    int bv = (b << 18) | v;
    int cnt = counts[bv];
    int off = offsets[bv];
    const float* row = attrs + ((size_t)(b * 32 + c)) * N;
    float m = -INFINITY;
    for (int k = 0; k < cnt; ++k) {
        m = fmaxf(m, row[sorted_idx[off + k]]);
    }
    vdata[((size_t)(b * 32 + c) << 18) | v] = (cnt > 0) ? m : 0.0f;
    if (c == 0) occ[bv] = (cnt >= MIN_PTS) ? 1.0f : 0.0f;
}

// ---------------------------------------------------------------------------
// FALLBACK PATH (R3): direct atomicMax into d_out, any C. (absmax 0, 1206us)
__device__ __forceinline__ unsigned enc_f32(float f) {
    unsigned u = __float_as_uint(f);
    return (u & 0x80000000u) ? ~u : (u | 0x80000000u);
}
__device__ __forceinline__ float dec_f32(unsigned u) {
    return (u & 0x80000000u) ? __uint_as_float(u & 0x7FFFFFFFu)
                             : __uint_as_float(~u);
}

__global__ void init_kernel(uint4* __restrict__ data4, uint4* __restrict__ cnt4,
                            int nData4, int nCnt4) {
    int i = blockIdx.x * blockDim.x + threadIdx.x;
    uint4 z = make_uint4(0u, 0u, 0u, 0u);
    if (i < nData4) data4[i] = z;
    else if (i < nData4 + nCnt4) cnt4[i - nData4] = z;
}

__global__ void scatter_kernel(const float* __restrict__ coords,
                               const float* __restrict__ attrs,
                               unsigned* __restrict__ bits,
                               int* __restrict__ counts,
                               int N, int C) {
    int n = blockIdx.x * blockDim.x + threadIdx.x;
    int b = blockIdx.y;
    if (n >= N) return;
    const float* pc = coords + (size_t)b * 3 * N;
    int ix = bin_coord(pc[n]);
    int iy = bin_coord(pc[n + N]);
    int iz = bin_coord(pc[n + 2 * N]);
    if ((unsigned)ix >= (unsigned)GW || (unsigned)iy >= (unsigned)GL ||
        (unsigned)iz >= (unsigned)GH)
        return;
    int v = (ix << 12) | (iy << 6) | iz;
    atomicAdd(&counts[b * GV + v], 1);
    const float* pa = attrs + (size_t)b * C * N + n;
    unsigned* pb = bits + (size_t)b * C * GV + v;
    for (int c = 0; c < C; ++c)
        atomicMax(&pb[(size_t)c * GV], enc_f32(pa[(size_t)c * N]));
}

__global__ void finalize_kernel(unsigned* __restrict__ data,
                                const int* __restrict__ counts,
                                float* __restrict__ occ, int C) {
    int i = blockIdx.x * blockDim.x + threadIdx.x;
    int nData4 = NB * C * GV / 4;
    int nOcc4 = NB * GV / 4;
    if (i < nData4) {
        int idx = i << 2;
        int v = idx & (GV - 1);
        int b = idx / (C * GV);
        int4 cv = *(const int4*)&counts[b * GV + v];
        uint4 u = *(const uint4*)&data[idx];
        float4 r;
        r.x = cv.x > 0 ? dec_f32(u.x) : 0.0f;
        r.y = cv.y > 0 ? dec_f32(u.y) : 0.0f;
        r.z = cv.z > 0 ? dec_f32(u.z) : 0.0f;
        r.w = cv.w > 0 ? dec_f32(u.w) : 0.0f;
        *(float4*)&data[idx] = r;
    } else if (i < nData4 + nOcc4) {
        int j = (i - nData4) << 2;
        int4 cv = *(const int4*)&counts[j];
        float4 r;
        r.x = cv.x >= MIN_PTS ? 1.0f : 0.0f;
        r.y = cv.y >= MIN_PTS ? 1.0f : 0.0f;
        r.z = cv.z >= MIN_PTS ? 1.0f : 0.0f;
        r.w = cv.w >= MIN_PTS ? 1.0f : 0.0f;
        *(float4*)&occ[j] = r;
    }
}

// ---------------------------------------------------------------------------
extern "C" void kernel_launch(void* const* d_in, const int* in_sizes, int n_in,
                              void* d_out, int out_size, void* d_ws, size_t ws_size,
                              hipStream_t stream) {
    const float* coords = (const float*)d_in[0];  // [B,3,N]
    const float* attrs  = (const float*)d_in[1];  // [B,C,N]
    int N = in_sizes[0] / (NB * 3);
    int C = in_sizes[1] / (NB * N);

    // ws prefix: counts[B*GV] | offsets[B*GV] | blocksums[4096]
    //            | vox[B*N] | rank[B*N] | sorted_idx[B*N]
    size_t wsCommon = (size_t)(2 * NB * GV + 4096 + 3 * NB * N) * 4;  // ~18MB
    size_t oneT  = (size_t)N * 32 * 4;        // 25.6MB, attrsT for one batch
    size_t fullT = (size_t)NB * N * 32 * 4;   // 102.4MB, attrsT for all

    if (C == 32 && ws_size >= wsCommon + oneT) {
        int* counts     = (int*)d_ws;
        int* offsets    = counts + (size_t)NB * GV;
        int* blocksums  = offsets + (size_t)NB * GV;
        int* vox        = blocksums + 4096;
        int* rank       = vox + (size_t)NB * N;
        int* sorted_idx = rank + (size_t)NB * N;
        float* attrsT   = (float*)(sorted_idx + (size_t)NB * N);
        float* vdata    = (float*)d_out;                      // [B,32,V]
        float* occp     = (float*)d_out + (size_t)NB * 32 * GV;

        bool full = (ws_size >= wsCommon + fullT);
        bool launched = false;

        if (full) {
            // ------------ R10: single cooperative mega-kernel ------------
            static int coopGrid = -2;   // -2 = not probed
            if (coopGrid == -2) {
                int maxB = 0;
                if (hipOccupancyMaxActiveBlocksPerMultiprocessor(
                        &maxB, mega_kernel, 256, 0) == hipSuccess && maxB > 0) {
                    int cus = 256;
                    int dev = 0;
                    static hipDeviceProp_t prop;
                    if (hipGetDevice(&dev) == hipSuccess &&
                        hipGetDeviceProperties(&prop, dev) == hipSuccess &&
                        prop.multiProcessorCount > 0)
                        cus = prop.multiProcessorCount;
                    coopGrid = maxB * cus;
                    if (coopGrid > 2048) coopGrid = 2048;
                } else {
                    coopGrid = 0;
                }
            }
            if (coopGrid > 0) {
                void* kargs[] = {
                    (void*)&coords, (void*)&attrs, (void*)&counts,
                    (void*)&offsets, (void*)&blocksums, (void*)&vox,
                    (void*)&rank, (void*)&sorted_idx, (void*)&attrsT,
                    (void*)&vdata, (void*)&occp, (void*)&N};
                hipError_t e = hipLaunchCooperativeKernel(
                    reinterpret_cast<const void*>(mega_kernel),
                    dim3((unsigned)coopGrid), dim3(256), kargs, 0, stream);
                if (e == hipSuccess) {
                    launched = true;
                } else {
                    (void)hipGetLastError();   // clear, fall through to R9
                    coopGrid = 0;              // don't retry next iteration
                }
            }
        }

        if (!launched) {
            // ------------ R9 multi-kernel path (proven, 300us) ------------
            int nCnt4 = NB * GV / 4;
            zero_kernel<<<(nCnt4 + 255) / 256, 256, 0, stream>>>(
                (uint4*)counts, nCnt4);
            dim3 pgrid((N + 255) / 256, NB);
            if (full) {
                hist_transpose_kernel<<<pgrid, 256, 0, stream>>>(
                    coords, attrs, counts, vox, rank, attrsT,
                    (size_t)N * 32, 0, N);
            } else {
                hist_kernel<<<pgrid, 256, 0, stream>>>(coords, counts, vox,
                                                       rank, N);
            }
            scan_blocks_kernel<<<NB * GV / 1024, 256, 0, stream>>>(
                counts, offsets, blocksums);
            scan_sums_kernel<<<1, 256, 0, stream>>>(blocksums);
            scan_add_kernel<<<NB * GV / 1024, 256, 0, stream>>>(offsets,
                                                                blocksums);
            scatter_idx_kernel<<<pgrid, 256, 0, stream>>>(vox, rank, offsets,
                                                          sorted_idx, N);
            if (full) {
                segmax4_kernel<<<dim3(GV / 64, NB), 256, 0, stream>>>(
                    attrsT, counts, offsets, sorted_idx, vdata, occp,
                    (size_t)N * 32, 0);
            } else {
                for (int b = 0; b < NB; ++b) {
                    transpose_kernel<<<dim3((N + 255) / 256, 1), 256, 0,
                                       stream>>>(attrs, attrsT, 0, b, N);
                    segmax4_kernel<<<dim3(GV / 64, 1), 256, 0, stream>>>(
                        attrsT, counts, offsets, sorted_idx, vdata, occp, 0, b);
                }
            }
        }
    } else if (C == 32 && ws_size >= wsCommon) {
        // ------------------- R4 path: index sort + per-channel gather -------
        int* counts     = (int*)d_ws;
        int* offsets    = counts + (size_t)NB * GV;
        int* blocksums  = offsets + (size_t)NB * GV;
        int* vox        = blocksums + 4096;
        int* rank       = vox + (size_t)NB * N;
        int* sorted_idx = rank + (size_t)NB * N;
        float* vdata    = (float*)d_out;
        float* occp     = (float*)d_out + (size_t)NB * 32 * GV;

        int nCnt4 = NB * GV / 4;
        zero_kernel<<<(nCnt4 + 255) / 256, 256, 0, stream>>>((uint4*)counts,
                                                             nCnt4);
        dim3 pgrid((N + 255) / 256, NB);
        hist_kernel<<<pgrid, 256, 0, stream>>>(coords, counts, vox, rank, N);
        scan_blocks_kernel<<<NB * GV / 1024, 256, 0, stream>>>(counts, offsets,
                                                               blocksums);
        scan_sums_kernel<<<1, 256, 0, stream>>>(blocksums);
        scan_add_kernel<<<NB * GV / 1024, 256, 0, stream>>>(offsets, blocksums);
        scatter_idx_kernel<<<pgrid, 256, 0, stream>>>(vox, rank, offsets,
                                                      sorted_idx, N);
        int segThreads = NB * 32 * GV;
        segmax_kernel<<<segThreads / 256, 256, 0, stream>>>(
            attrs, counts, offsets, sorted_idx, vdata, occp, N);
    } else {
        unsigned* bits = (unsigned*)d_out;
        float* occp = (float*)d_out + (size_t)NB * C * GV;
        int* counts = (int*)d_ws;
        int nData4 = NB * C * GV / 4;
        int nCnt4 = NB * GV / 4;
        int initTotal = nData4 + nCnt4;
        init_kernel<<<(initTotal + 255) / 256, 256, 0, stream>>>(
            (uint4*)d_out, (uint4*)d_ws, nData4, nCnt4);
        dim3 sgrid((N + 255) / 256, NB);
        scatter_kernel<<<sgrid, 256, 0, stream>>>(coords, attrs, bits, counts,
                                                  N, C);
        finalize_kernel<<<(initTotal + 255) / 256, 256, 0, stream>>>(
            bits, counts, occp, C);
    }
}